// Round 2
// baseline (155.562 us; speedup 1.0000x reference)
//
#include <hip/hip_runtime.h>
#include <hip/hip_bf16.h>

typedef __bf16 bf16;
typedef __bf16 bf16x8 __attribute__((ext_vector_type(8)));
typedef float f32x4 __attribute__((ext_vector_type(4)));

__device__ __forceinline__ void gload_lds16(const void* g, void* l) {
  __builtin_amdgcn_global_load_lds(
      (const __attribute__((address_space(1))) void*)g,
      (__attribute__((address_space(3))) void*)l, 16, 0, 0);
}

// ---------------------------------------------------------------------------
// 256x256 8-phase GEMM: C = A[M,K] @ B[N,K]^T, bf16 in, f32 accum.
// EPI=0: f32 store. EPI=1: sigmoid -> bf16 store.
// 512 threads = 8 waves (2M x 4N). BK=64. LDS 128KB, 2 K-tile double buffer.
// Half-tile = 256 rows x 32 k-cols (16KB contiguous), 2 gload_lds16/thread.
// Per tile: 4 phases {ds_read; stage half 4t+6+q; bar; lgkm0; 16 MFMA; bar},
// vmcnt(4) at each tile boundary (counted, never drained except last).
// Swizzle: colbyte ^= ((row>>1)&3)<<4 on stage-source AND ds_read (involution).
// ---------------------------------------------------------------------------
#define PHASE(t_, KK, QM, READB, STG_T, STG_IDX, DO_STG, ...)                   \
  {                                                                             \
    const int bufb = ((t_)&1) << 16;                                            \
    _Pragma("unroll") for (int i = 0; i < 4; ++i)                               \
        afr[i] = *(const bf16x8*)(smem + bufb + ((KK) << 14) + abase0 +         \
                                  ((QM)*4 + i) * 1024);                         \
    if (READB) {                                                                \
      _Pragma("unroll") for (int j = 0; j < 4; ++j)                             \
          bfr[j] = *(const bf16x8*)(smem + bufb + (1 << 15) + ((KK) << 14) +    \
                                    bbase0 + j * 1024);                         \
    }                                                                           \
    if (DO_STG) stage((STG_T), (STG_IDX), (STG_T)&1);                           \
    __builtin_amdgcn_s_barrier();                                               \
    asm volatile("s_waitcnt lgkmcnt(0)" ::: "memory");                          \
    __builtin_amdgcn_sched_barrier(0);                                          \
    __builtin_amdgcn_s_setprio(1);                                              \
    _Pragma("unroll") for (int i = 0; i < 4; ++i)                               \
      _Pragma("unroll") for (int j = 0; j < 4; ++j)                             \
        acc[(QM)*4 + i][j] = __builtin_amdgcn_mfma_f32_16x16x32_bf16(           \
            afr[i], bfr[j], acc[(QM)*4 + i][j], 0, 0, 0);                       \
    __builtin_amdgcn_s_setprio(0);                                              \
    __builtin_amdgcn_sched_barrier(0);                                          \
    __VA_ARGS__;                                                                \
    __builtin_amdgcn_s_barrier();                                               \
  }

template <int EPI>
__global__ __launch_bounds__(512, 2) void gemm8p(
    const bf16* __restrict__ A, const bf16* __restrict__ Bw,
    void* __restrict__ C, int M, int N, int K) {
  __shared__ __align__(16) char smem[131072];
  const int tid = threadIdx.x;
  const int lane = tid & 63;
  const int wave = tid >> 6;
  const int wr = wave >> 2;  // 0..1  (M dir)
  const int wc = wave & 3;   // 0..3  (N dir)

  const int nbN = N >> 8;
  const int nwg = gridDim.x;
  const int q8 = nwg >> 3;  // grids divisible by 8
  const int tile = ((int)blockIdx.x & 7) * q8 + ((int)blockIdx.x >> 3);
  const int m0 = (tile / nbN) << 8;
  const int n0 = (tile % nbN) << 8;

  // ---- staging per-thread constants (linear LDS dest, pre-swizzled source) --
  const int srow = tid >> 2;                                  // q=0 row (q=1:+128)
  const int clog = ((tid & 3) << 4) ^ (((srow >> 1) & 3) << 4);  // source col bytes
  const int ldsw = wave << 10;  // wave-uniform part of dest

  auto stage = [&](int tileT, int idx, int buf) {
    const int isB = idx & 1, kk = idx >> 1;
    const int halfbase = (buf << 16) + (isB << 15) + (kk << 14);
    const bf16* src = isB ? Bw : A;
    const int rbase = isB ? n0 : m0;
    const int gk = (tileT << 6) + (kk << 5);  // k element offset
#pragma unroll
    for (int q = 0; q < 2; ++q) {
      const int rl = srow + q * 128;
      const char* gsrc = (const char*)(src + (size_t)(rbase + rl) * K + gk) + clog;
      gload_lds16(gsrc, smem + halfbase + q * 8192 + ldsw);
    }
  };

  // ---- ds_read per-lane constants ----
  const int lrow = lane & 15;
  const int rdofs = (((lane >> 4) & 3) << 4) ^ (((lrow >> 1) & 3) << 4);
  const int abase0 = wr * 8192 + lrow * 64 + rdofs;   // + qmfrag*1024 + kk*16384 + buf
  const int bbase0 = wc * 4096 + lrow * 64 + rdofs;   // + nfrag*1024 (+32KB B region)

  f32x4 acc[8][4] = {};
  bf16x8 afr[4], bfr[4];

  const int nt = K >> 6;  // 16 for K=1024

  // ---- prologue: stage halves 0..5 (tile0 full + tile1 A-k0,B-k0) ----
  stage(0, 0, 0); stage(0, 1, 0); stage(0, 2, 0); stage(0, 3, 0);
  stage(1, 0, 1); stage(1, 1, 1);
  asm volatile("s_waitcnt vmcnt(4)" ::: "memory");  // tile0 fully landed
  __builtin_amdgcn_s_barrier();

  for (int t = 0; t < nt; ++t) {
    const bool s01 = (t < nt - 1);  // stage halves 4t+6,4t+7 (tile t+1 k1)
    const bool s23 = (t < nt - 2);  // stage halves 4t+8,4t+9 (tile t+2 k0)
    PHASE(t, 0, 0, true,  t + 1, 2, s01)
    PHASE(t, 0, 1, false, t + 1, 3, s01)
    PHASE(t, 1, 0, true,  t + 2, 0, s23)
    PHASE(t, 1, 1, false, t + 2, 1, s23,
          if (t == nt - 2) { asm volatile("s_waitcnt vmcnt(0)" ::: "memory"); }
          else if (t < nt - 2) { asm volatile("s_waitcnt vmcnt(4)" ::: "memory"); })
  }

  // ---- epilogue: C/D layout col=lane&15, row=(lane>>4)*4+reg ----
  const int col0 = n0 + (wc << 6) + lrow;
  const int rowb = m0 + (wr << 7) + ((lane >> 4) << 2);
#pragma unroll
  for (int i = 0; i < 8; ++i)
#pragma unroll
    for (int j = 0; j < 4; ++j)
#pragma unroll
      for (int r = 0; r < 4; ++r) {
        const size_t idx = (size_t)(rowb + i * 16 + r) * N + (col0 + j * 16);
        const float v = acc[i][j][r];
        if (EPI == 1) {
          ((bf16*)C)[idx] = (bf16)(1.0f / (1.0f + __expf(-v)));
        } else {
          ((float*)C)[idx] = v;
        }
      }
}

// ---------------------------------------------------------------------------
// Windowed Hamming attention + gate.  One thread per (b,s,h).
// ---------------------------------------------------------------------------
__global__ __launch_bounds__(256) void rosa_attn(
    const bf16* __restrict__ qkv, const float* __restrict__ emb0,
    const float* __restrict__ emb1, bf16* __restrict__ G) {
  const int t = blockIdx.x * 256 + threadIdx.x;
  const int row = t >> 7;
  const int h = t & 127;
  const int sp = row & 4095;

  const bf16* qptr = qkv + (size_t)row * 3072 + h * 8;
  bf16x8 qv = *(const bf16x8*)qptr;
  float qb[8], qsum = 0.f;
#pragma unroll
  for (int c = 0; c < 8; ++c) {
    qb[c] = (float)qv[c];
    qsum += qb[c];
  }

  float oacc[8] = {};
  float wsum = 0.f;
  const int wmax = (sp + 1 < 8) ? (sp + 1) : 8;
  const float scale = 0.35355339059327373f;

  for (int d = 0; d < wmax; ++d) {
    const bf16* base = qkv + (size_t)(row - d) * 3072 + h * 8;
    bf16x8 kv = *(const bf16x8*)(base + 1024);
    bf16x8 vv = *(const bf16x8*)(base + 2048);
    float dot = 0.f, ksum = 0.f;
#pragma unroll
    for (int c = 0; c < 8; ++c) {
      const float kb = (float)kv[c];
      dot += qb[c] * kb;
      ksum += kb;
    }
    const float score = (8.0f + 2.0f * dot - qsum - ksum) * scale;
    const float w = __expf(score);
    wsum += w;
#pragma unroll
    for (int c = 0; c < 8; ++c) oacc[c] += w * (float)vv[c];
  }

  const float inv = 1.0f / wsum;
  const int e0i = h * 8;
  bf16x8 outv;
#pragma unroll
  for (int c = 0; c < 8; ++c) {
    const float o = oacc[c] * inv;
    const float e0 = emb0[e0i + c], e1 = emb1[e0i + c];
    outv[c] = (bf16)(e0 + (e1 - e0) * o);
  }
  *(bf16x8*)(G + (size_t)row * 1024 + h * 8) = outv;
}

// ---------------------------------------------------------------------------
__global__ __launch_bounds__(256) void cvt_f32_bf16(
    const float* __restrict__ src, bf16* __restrict__ dst, int n) {
  const int i = (blockIdx.x * 256 + threadIdx.x) * 8;
  if (i >= n) return;
  const float4 a = *(const float4*)(src + i);
  const float4 b = *(const float4*)(src + i + 4);
  bf16x8 o;
  o[0] = (bf16)a.x; o[1] = (bf16)a.y; o[2] = (bf16)a.z; o[3] = (bf16)a.w;
  o[4] = (bf16)b.x; o[5] = (bf16)b.y; o[6] = (bf16)b.z; o[7] = (bf16)b.w;
  *(bf16x8*)(dst + i) = o;
}

// ---------------------------------------------------------------------------
extern "C" void kernel_launch(void* const* d_in, const int* in_sizes, int n_in,
                              void* d_out, int out_size, void* d_ws,
                              size_t ws_size, hipStream_t stream) {
  const float* X = (const float*)d_in[0];
  const float* Wq = (const float*)d_in[1];
  const float* Wk = (const float*)d_in[2];
  const float* Wv = (const float*)d_in[3];
  const float* Wo = (const float*)d_in[4];
  const float* emb0 = (const float*)d_in[5];
  const float* emb1 = (const float*)d_in[6];

  char* ws = (char*)d_ws;
  bf16* Xb    = (bf16*)(ws + 0);          // 8192*1024   (16 MB)
  bf16* Wqkvb = (bf16*)(ws + 16777216);   // 3072*1024   (6 MB)
  bf16* Wob   = (bf16*)(ws + 23068672);   // 1024*1024   (2 MB)
  bf16* QKVb  = (bf16*)(ws + 25165824);   // 8192*3072   (48 MB)
  bf16* G     = (bf16*)(ws + 75497472);   // 8192*1024   (16 MB)
  float* out  = (float*)d_out;

  cvt_f32_bf16<<<4096, 256, 0, stream>>>(X, Xb, 8388608);
  cvt_f32_bf16<<<512, 256, 0, stream>>>(Wq, Wqkvb, 1048576);
  cvt_f32_bf16<<<512, 256, 0, stream>>>(Wk, Wqkvb + 1048576, 1048576);
  cvt_f32_bf16<<<512, 256, 0, stream>>>(Wv, Wqkvb + 2097152, 1048576);
  cvt_f32_bf16<<<512, 256, 0, stream>>>(Wo, Wob, 1048576);

  // fused QKV projection + sigmoid -> bf16 (M=8192, N=3072, K=1024)
  gemm8p<1><<<384, 512, 0, stream>>>(Xb, Wqkvb, QKVb, 8192, 3072, 1024);

  // windowed attention + gate -> bf16
  rosa_attn<<<4096, 256, 0, stream>>>(QKVb, emb0, emb1, G);

  // output projection -> f32 (M=8192, N=1024, K=1024)
  gemm8p<0><<<128, 512, 0, stream>>>(G, Wob, out, 8192, 1024, 1024);
}